// Round 2
// baseline (373.319 us; speedup 1.0000x reference)
//
#include <hip/hip_runtime.h>

#define Bb 256
#define Tt 512
#define Kk 128

using short8  = __attribute__((ext_vector_type(8))) short;
using floatx4 = __attribute__((ext_vector_type(4))) float;

// fp32 -> bf16 round-to-nearest-even (positive finite inputs only)
__device__ __forceinline__ unsigned short f2bf(float x) {
    unsigned u = __float_as_uint(x);
    unsigned r = ((u >> 16) & 1u) + 0x7fffu;
    return (unsigned short)((u + r) >> 16);
}

// finalize logz for rows frozen at step TPREV (partials written pre-barrier)
#define CRF_FINALIZE(TPREV) do {                                              \
    unsigned fm_ = maskbuf[(TPREV)];                                          \
    if (fm_ && tid < 16 && ((fm_ >> tid) & 1u)) {                             \
        float ssum_ = 0.f;                                                    \
        _Pragma("unroll")                                                     \
        for (int i_ = 0; i_ < 8; ++i_) ssum_ += partials[i_][tid];            \
        atomicAdd(out, __logf(ssum_) + (float)Csum * 0.69314718056f);         \
    }                                                                         \
} while (0)

// write row-sum partials for rows freezing at this step (AV = u(t) values)
#define CRF_FREEZE_PART(AV, MASKVAL) do {                                     \
    unsigned m_ = (MASKVAL);                                                  \
    while (m_) {                                                              \
        int b_ = __builtin_ctz(m_); m_ &= m_ - 1;                             \
        int rr_ = b_ & 3, gg_ = b_ >> 2;                                      \
        _Pragma("unroll")                                                     \
        for (int nt_ = 0; nt_ < 2; ++nt_) {                                   \
            float v_ = (rr_ == 0) ? AV[nt_][0] : (rr_ == 1) ? AV[nt_][1]      \
                     : (rr_ == 2) ? AV[nt_][2] : AV[nt_][3];                  \
            v_ += __shfl_xor(v_, 1, 64); v_ += __shfl_xor(v_, 2, 64);         \
            v_ += __shfl_xor(v_, 4, 64); v_ += __shfl_xor(v_, 8, 64);         \
            if (q == gg_ && c == 0) partials[2 * wave + nt_][b_] = v_;        \
        }                                                                     \
    }                                                                         \
} while (0)

// one forward step; LBUF holds raw logits(t), reloaded with logits(t+2)
#define CRF_STEP(TV, LBUF) do {                                               \
    const int t_ = (TV);                                                      \
    CRF_FINALIZE(t_ - 1);                                                     \
    float pv_[8];                                                             \
    _Pragma("unroll")                                                         \
    for (int i_ = 0; i_ < 8; ++i_) pv_[i_] = __expf(LBUF[i_]);                \
    int tc_ = t_ + 2; if (tc_ > Tt - 1) tc_ = Tt - 1;                         \
    _Pragma("unroll")                                                         \
    for (int nt = 0; nt < 2; ++nt)                                            \
        _Pragma("unroll")                                                     \
        for (int r = 0; r < 4; ++r)                                           \
            LBUF[nt * 4 + r] = lp[r][(size_t)tc_ * Kk + 16 * nt];             \
    unsigned short srefb_ = uLDS[(t_ - 1) & 1][0][0];                         \
    int efield_ = (int)((srefb_ >> 7) & 0xffu);                               \
    float sc_ = __uint_as_float((unsigned)(254 - efield_) << 23); /* 2^-e */  \
    floatx4 acc0_ = {0.f, 0.f, 0.f, 0.f};                                     \
    floatx4 acc1_ = {0.f, 0.f, 0.f, 0.f};                                     \
    const int ab_ = (t_ - 1) & 1;                                             \
    _Pragma("unroll")                                                         \
    for (int s4 = 0; s4 < 4; ++s4) {                                          \
        short8 A_ = *(const short8*)&uLDS[ab_][c][32 * s4 + 8 * q];           \
        acc0_ = __builtin_amdgcn_mfma_f32_16x16x32_bf16(A_, Efrag[s4][0],     \
                                                        acc0_, 0, 0, 0);      \
        acc1_ = __builtin_amdgcn_mfma_f32_16x16x32_bf16(A_, Efrag[s4][1],     \
                                                        acc1_, 0, 0, 0);      \
    }                                                                         \
    _Pragma("unroll")                                                         \
    for (int r = 0; r < 4; ++r) {                                             \
        av[0][r] = acc0_[r] * pv_[r] * sc_;                                   \
        av[1][r] = acc1_[r] * pv_[4 + r] * sc_;                               \
    }                                                                         \
    { unsigned wm_ = maskbuf[t_]; if (wm_) CRF_FREEZE_PART(av, wm_); }        \
    _Pragma("unroll")                                                         \
    for (int nt = 0; nt < 2; ++nt)                                            \
        _Pragma("unroll")                                                     \
        for (int r = 0; r < 4; ++r)                                           \
            uLDS[t_ & 1][4 * q + r][32 * wave + 16 * nt + c] =                \
                f2bf(av[nt][r]);                                              \
    Csum += efield_ - 127;                                                    \
    __syncthreads();                                                          \
} while (0)

// 16 blocks x 256 threads. Block handles 16 batches; wave w owns N-tiles
// {2w,2w+1} (states 32w..32w+31). C/D layout: col=lane&15, row=(lane>>4)*4+reg
// (m89/m91). A: A[m=lane&15][k=quad*8+j] (m120). B mirrors A. Any error in the
// (quad,j)->k mapping cancels (same sigma used for A and B fills).
__global__ __launch_bounds__(256, 1) void crf_mfma_kernel(
    const float* __restrict__ logits,   // B*T*K fp32
    const int*   __restrict__ labels,   // B*T   int32
    const int*   __restrict__ seq_lens, // B     int32
    const float* __restrict__ trans,    // K*K   fp32
    float* __restrict__ out)            // 1     fp32 (pre-zeroed)
{
    __shared__ __align__(16) unsigned short uLDS[2][16][136]; // bf16, +8 pad
    __shared__ float partials[8][16];
    __shared__ unsigned int maskbuf[Tt];
    __shared__ float scoreRed[4];
    __shared__ int LmaxSh;

    const int tid  = threadIdx.x;
    const int lane = tid & 63;
    const int wave = tid >> 6;
    const int q    = lane >> 4;    // quad
    const int c    = lane & 15;    // col (C layout) / m (A frag) / n (B frag)
    const int bbase = blockIdx.x * 16;

    for (int i = tid; i < Tt; i += 256) maskbuf[i] = 0u;
    if (tid == 0) LmaxSh = 0;
    __syncthreads();

    if (tid < 16) {
        int L = seq_lens[bbase + tid];
        atomicOr(&maskbuf[L - 1], 1u << tid);
        atomicMax(&LmaxSh, L);
    }

    // ---- gold-path score: 16 threads per batch ----
    {
        const int b = bbase + (tid >> 4);
        const int L = seq_lens[b];
        const int* lab = labels + b * Tt;
        const float* lg = logits + (size_t)b * Tt * Kk;
        float s = 0.f;
        for (int t0 = (tid & 15); t0 < Tt; t0 += 16) {
            if (t0 < L) {
                int l1 = lab[t0];
                s += lg[(size_t)t0 * Kk + l1];
                if (t0 >= 1) s += trans[lab[t0 - 1] * Kk + l1];
            }
        }
        #pragma unroll
        for (int o = 32; o > 0; o >>= 1) s += __shfl_down(s, o, 64);
        if (lane == 0) scoreRed[wave] = s;
    }
    __syncthreads();
    if (tid == 0)
        atomicAdd(out, -(scoreRed[0] + scoreRed[1] + scoreRed[2] + scoreRed[3]));
    const int Lmax = LmaxSh;

    // ---- E = exp(trans) into B-frag registers (constant all steps) ----
    short8 Efrag[4][2];
    #pragma unroll
    for (int s4 = 0; s4 < 4; ++s4)
        #pragma unroll
        for (int nt = 0; nt < 2; ++nt) {
            short8 f;
            #pragma unroll
            for (int j = 0; j < 8; ++j) {
                int k = 32 * s4 + 8 * q + j;
                int n = 32 * wave + 16 * nt + c;
                f[j] = (short)f2bf(__expf(trans[k * Kk + n]));
            }
            Efrag[s4][nt] = f;
        }

    // per-lane logit base pointers (C-layout element addressing)
    const float* lp[4];
    #pragma unroll
    for (int r = 0; r < 4; ++r)
        lp[r] = logits + (size_t)(bbase + 4 * q + r) * Tt * Kk + 32 * wave + c;

    // ---- step 0: u(0) = exp(logits[:,0,:]) in C-layout regs ----
    float av[2][4];
    #pragma unroll
    for (int nt = 0; nt < 2; ++nt)
        #pragma unroll
        for (int r = 0; r < 4; ++r)
            av[nt][r] = __expf(lp[r][16 * nt]);
    int Csum = 0;

    { unsigned wm = maskbuf[0]; if (wm) CRF_FREEZE_PART(av, wm); }
    #pragma unroll
    for (int nt = 0; nt < 2; ++nt)
        #pragma unroll
        for (int r = 0; r < 4; ++r)
            uLDS[0][4 * q + r][32 * wave + 16 * nt + c] = f2bf(av[nt][r]);

    // prefetch logits for steps 1 and 2 (static reg buffers la/lb)
    float la[8], lb[8];
    #pragma unroll
    for (int nt = 0; nt < 2; ++nt)
        #pragma unroll
        for (int r = 0; r < 4; ++r) {
            la[nt * 4 + r] = lp[r][(size_t)1 * Kk + 16 * nt];
            lb[nt * 4 + r] = lp[r][(size_t)2 * Kk + 16 * nt];
        }
    __syncthreads();

    // ---- forward recursion ----
    int t = 1;
    while (t + 1 < Lmax) {
        CRF_STEP(t, la);
        CRF_STEP(t + 1, lb);
        t += 2;
    }
    if (t < Lmax) CRF_STEP(t, la);
    CRF_FINALIZE(Lmax - 1);
}

extern "C" void kernel_launch(void* const* d_in, const int* in_sizes, int n_in,
                              void* d_out, int out_size, void* d_ws, size_t ws_size,
                              hipStream_t stream) {
    const float* logits   = (const float*)d_in[0];
    const int*   labels   = (const int*)d_in[1];
    const int*   seq_lens = (const int*)d_in[2];
    const float* trans    = (const float*)d_in[3];
    float* out = (float*)d_out;

    hipMemsetAsync(out, 0, sizeof(float), stream);
    crf_mfma_kernel<<<dim3(Bb / 16), dim3(256), 0, stream>>>(
        logits, labels, seq_lens, trans, out);
}